// Round 6
// baseline (189.388 us; speedup 1.0000x reference)
//
#include <hip/hip_runtime.h>
#include <math.h>

#define BB 256
#define DD 5120
#define NN 16
#define RR 160
#define CT 192          // 160 (t) + 16 (Bm) + 16 (Cm)
#define NSPLIT 160      // k-splits of 32 (160 * 32 = 5120)
#define KSPLIT 32
#define TMP_ELEMS (BB * CT)          // 49152
#define NEGA_ELEMS (DD * NN)         // 81920

// ---------------- K1: partials[s][b][c] = x[b, ks:ks+32] @ Wcat[ks:ks+32, c]
// Round-1 tile/micro structure, but ONE 32-k step per block: no inner-loop
// barrier phases. grid (3 c, 4 b, 160 ksplits) = 1920 blocks = 7.5 blocks/CU.
__global__ __launch_bounds__(256) void k1_gemm(const float* __restrict__ x,
                                               const float* __restrict__ Wxdt,
                                               const float* __restrict__ Wbc,
                                               float* __restrict__ part) {
    __shared__ float xs[32][68];   // [k][b] transposed (68: b128-aligned rows)
    __shared__ float ws[32][64];   // [k][c]
    const int tid = threadIdx.x;
    const int tx = tid & 15, ty = tid >> 4;
    const int c0 = blockIdx.x * 64;
    const int b0 = blockIdx.y * 64;
    const int k0 = blockIdx.z * KSPLIT;

    // stage x tile transposed into LDS (64 b-rows x 32 k)
    {
        const int i  = tid >> 3;          // 0..31
        const int j4 = (tid & 7) * 4;     // 0..28
        #pragma unroll
        for (int rep = 0; rep < 2; ++rep) {
            const int row = i + rep * 32;
            const float4 v = *(const float4*)&x[(size_t)(b0 + row) * DD + k0 + j4];
            xs[j4 + 0][row] = v.x;
            xs[j4 + 1][row] = v.y;
            xs[j4 + 2][row] = v.z;
            xs[j4 + 3][row] = v.w;
        }
    }
    // stage W tile (float4 along c; both sources are %4 aligned)
    {
        const int c4 = (tid & 15) * 4;
        const int r0 = tid >> 4;          // 0..15
        #pragma unroll
        for (int rep = 0; rep < 2; ++rep) {
            const int r  = r0 + rep * 16;
            const int kg = k0 + r;
            const int cg = c0 + c4;
            float4 v;
            if (cg < RR) v = *(const float4*)&Wxdt[(size_t)kg * RR + cg];
            else         v = *(const float4*)&Wbc[(size_t)kg * 32 + (cg - RR)];
            *(float4*)&ws[r][c4] = v;
        }
    }
    __syncthreads();

    float acc[4][4] = {};
    #pragma unroll
    for (int k = 0; k < KSPLIT; ++k) {
        const float4 a4 = *(const float4*)&xs[k][ty * 4];
        const float4 w4 = *(const float4*)&ws[k][tx * 4];
        const float av[4] = {a4.x, a4.y, a4.z, a4.w};
        const float wv[4] = {w4.x, w4.y, w4.z, w4.w};
        #pragma unroll
        for (int u = 0; u < 4; ++u)
            #pragma unroll
            for (int v = 0; v < 4; ++v)
                acc[u][v] = fmaf(av[u], wv[v], acc[u][v]);
    }

    float* p = part + (size_t)blockIdx.z * TMP_ELEMS;
    #pragma unroll
    for (int u = 0; u < 4; ++u) {
        const int b = b0 + ty * 4 + u;
        *(float4*)&p[b * CT + c0 + tx * 4] =
            make_float4(acc[u][0], acc[u][1], acc[u][2], acc[u][3]);
    }
}

// ---------------- K_RED: tmp = sum_s partials; negA = -exp(A_log) -----------
// grid: 512 blocks x 256 = 131072 = 49152 + 81920
__global__ __launch_bounds__(256) void k_red(const float* __restrict__ part,
                                             const float* __restrict__ Alog,
                                             float* __restrict__ tmp,
                                             float* __restrict__ negA) {
    const int idx = blockIdx.x * 256 + threadIdx.x;
    if (idx < TMP_ELEMS) {
        float s = 0.f;
        #pragma unroll 8
        for (int z = 0; z < NSPLIT; ++z) s += part[(size_t)z * TMP_ELEMS + idx];
        tmp[idx] = s;
    } else {
        const int j = idx - TMP_ELEMS;
        negA[j] = -__expf(Alog[j]);
    }
}

// ---------------- K_FUSED: dt dot-product + SSM epilogue --------------------
// dt[b,d] = softplus(sum_k t[b,k]*Wdt[k,d] + bdt[d])
// y[b,d]  = sum_n (exp(negA[d,n]*dt)*h0[b,d,n] + dt*x*Bm[b,n]) * Cm[b,n] + x
// v4: 2 b per thread (grid 2560 blocks = 8 blocks/CU = up to 32 waves/CU,
// VGPR kept <= 64) for 2x the latency-hiding waves; h0/x PREFETCHED before
// the dt loop (their ~900cy latency hides under 160-deep FMA chain) while t
// stays in LDS (the confound that broke the r4 attempt). negA loaded after
// the dt loop to cap prefetch register pressure.
__global__ __launch_bounds__(256) void k_fused(const float* __restrict__ x,
                                               const float* __restrict__ h0,
                                               const float* __restrict__ Wdt,
                                               const float* __restrict__ bdt,
                                               const float* __restrict__ tmp,
                                               const float* __restrict__ negA,
                                               float* __restrict__ out) {
    __shared__ float ts[2][CT];        // 2 rows of t(160)+Bm(16)+Cm(16)
    const int tid = threadIdx.x;
    const int b0 = blockIdx.x * 2;     // fast axis: shares Wdt panel
    const int d  = blockIdx.y * 256 + tid;

    // stage 2 t/BC rows (384 floats), coalesced, one barrier
    for (int p = tid; p < 2 * CT; p += 256)
        ts[p / CT][p % CT] = tmp[(size_t)b0 * CT + p];
    __syncthreads();

    // ---- prefetch h0 + x (latency hides under the dt loop below) ----
    float4 h4[2][4];
    float  xe[2];
    #pragma unroll
    for (int bi = 0; bi < 2; ++bi) {
        const size_t cell = (size_t)(b0 + bi) * DD + d;
        xe[bi] = x[cell];
        const float* hp = &h0[cell * NN];
        #pragma unroll
        for (int j = 0; j < 4; ++j) h4[bi][j] = *(const float4*)&hp[j * 4];
    }

    // ---- dt dot-product: only Wdt touches vmem; t from LDS broadcast ----
    const float* wcol = Wdt + d;
    float acc[2] = {0.f, 0.f};
    #pragma unroll 2
    for (int k8 = 0; k8 < RR; k8 += 8) {
        float w[8];
        #pragma unroll
        for (int j = 0; j < 8; ++j) w[j] = wcol[(size_t)(k8 + j) * DD];
        #pragma unroll
        for (int bi = 0; bi < 2; ++bi) {
            const float* tr = &ts[bi][k8];
            #pragma unroll
            for (int j = 0; j < 8; ++j)
                acc[bi] = fmaf(tr[j], w[j], acc[bi]);
        }
    }

    // negA[d, 0..15] into registers (after dt loop: caps prefetch VGPR)
    float av[16];
    {
        const float* ap = &negA[(size_t)d * NN];
        #pragma unroll
        for (int n4 = 0; n4 < NN; n4 += 4) {
            const float4 a4 = *(const float4*)&ap[n4];
            av[n4 + 0] = a4.x; av[n4 + 1] = a4.y;
            av[n4 + 2] = a4.z; av[n4 + 3] = a4.w;
        }
    }
    const float bdv = bdt[d];

    // ---- epilogue: softplus + SSM, consuming prefetched registers ----
    #pragma unroll
    for (int bi = 0; bi < 2; ++bi) {
        const float z  = acc[bi] + bdv;
        const float dt = fmaxf(z, 0.f) + log1pf(__expf(-fabsf(z)));  // softplus
        const size_t cell = (size_t)(b0 + bi) * DD + d;
        const float dtx = dt * xe[bi];
        const float* bm = &ts[bi][RR];       // Bm from LDS (broadcast)
        const float* cm = &ts[bi][RR + 16];  // Cm from LDS
        float acc4[4] = {xe[bi], 0.f, 0.f, 0.f};
        #pragma unroll
        for (int j = 0; j < 4; ++j) {
            const float hv[4] = {h4[bi][j].x, h4[bi][j].y, h4[bi][j].z, h4[bi][j].w};
            #pragma unroll
            for (int q = 0; q < 4; ++q) {
                const int n = j * 4 + q;
                const float dA = __expf(av[n] * dt);
                const float h  = fmaf(dA, hv[q], dtx * bm[n]);
                acc4[q] = fmaf(h, cm[n], acc4[q]);
            }
        }
        out[cell] = (acc4[0] + acc4[1]) + (acc4[2] + acc4[3]);
    }
}

extern "C" void kernel_launch(void* const* d_in, const int* in_sizes, int n_in,
                              void* d_out, int out_size, void* d_ws, size_t ws_size,
                              hipStream_t stream) {
    const float* x    = (const float*)d_in[0];
    const float* h0   = (const float*)d_in[1];
    const float* Wxdt = (const float*)d_in[2];
    const float* Wdt  = (const float*)d_in[3];
    const float* bdt  = (const float*)d_in[4];
    const float* Wbc  = (const float*)d_in[5];
    const float* Alog = (const float*)d_in[6];
    float* out = (float*)d_out;

    // ws layout (floats): partials[160*49152] (31.5 MB) | tmp[49152] | negA[81920]
    float* part = (float*)d_ws;
    float* tmp  = part + (size_t)NSPLIT * TMP_ELEMS;
    float* negA = tmp + TMP_ELEMS;

    k1_gemm<<<dim3(3, 4, NSPLIT), 256, 0, stream>>>(x, Wxdt, Wbc, part);
    k_red<<<dim3((TMP_ELEMS + NEGA_ELEMS) / 256), 256, 0, stream>>>(part, Alog, tmp, negA);
    k_fused<<<dim3(BB / 2, DD / 256), 256, 0, stream>>>(x, h0, Wdt, bdt, tmp, negA, out);
}

// Round 8
// 178.659 us; speedup vs baseline: 1.0600x; 1.0600x over previous
//
#include <hip/hip_runtime.h>
#include <math.h>

#define BB 256
#define DD 5120
#define NN 16
#define RR 160
#define CT 192          // 160 (t) + 16 (Bm) + 16 (Cm)
#define NSPLIT 32
#define TMP_ELEMS (BB * CT)          // 49152
#define NEGA_ELEMS (DD * NN)         // 81920

typedef float vfloat4 __attribute__((ext_vector_type(4)));  // clang-native: OK for nontemporal builtins

// ---------------- K1: partials[s][b][c] = x[b, ks:ks+160] @ Wcat[ks:ks+160, c]
// grid: (3 c-tiles, 4 b-tiles, 32 k-splits), block 256. No atomics.
// (Exact round-1 version — part of the measured-best 175 us configs.)
__global__ __launch_bounds__(256) void k1_gemm(const float* __restrict__ x,
                                               const float* __restrict__ Wxdt,
                                               const float* __restrict__ Wbc,
                                               float* __restrict__ part) {
    __shared__ float xs[32][68];   // [k][b] transposed (68: b128-aligned rows)
    __shared__ float ws[32][64];   // [k][c]
    const int tid = threadIdx.x;
    const int tx = tid & 15, ty = tid >> 4;
    const int c0 = blockIdx.x * 64;
    const int b0 = blockIdx.y * 64;
    const int k0 = blockIdx.z * 160;
    float acc[4][4] = {};

    for (int kc = 0; kc < 160; kc += 32) {
        // stage x tile transposed into LDS
        {
            const int i  = tid >> 3;          // 0..31
            const int j4 = (tid & 7) * 4;     // 0..28
            #pragma unroll
            for (int rep = 0; rep < 2; ++rep) {
                const int row = i + rep * 32;
                const float4 v = *(const float4*)&x[(size_t)(b0 + row) * DD + k0 + kc + j4];
                xs[j4 + 0][row] = v.x;
                xs[j4 + 1][row] = v.y;
                xs[j4 + 2][row] = v.z;
                xs[j4 + 3][row] = v.w;
            }
        }
        // stage W tile (float4 along c; both sources are %4 aligned)
        {
            const int c4 = (tid & 15) * 4;
            const int r0 = tid >> 4;          // 0..15
            #pragma unroll
            for (int rep = 0; rep < 2; ++rep) {
                const int r  = r0 + rep * 16;
                const int kg = k0 + kc + r;
                const int cg = c0 + c4;
                float4 v;
                if (cg < RR) v = *(const float4*)&Wxdt[(size_t)kg * RR + cg];
                else         v = *(const float4*)&Wbc[(size_t)kg * 32 + (cg - RR)];
                *(float4*)&ws[r][c4] = v;
            }
        }
        __syncthreads();
        #pragma unroll
        for (int k = 0; k < 32; ++k) {
            const float4 a4 = *(const float4*)&xs[k][ty * 4];
            const float4 w4 = *(const float4*)&ws[k][tx * 4];
            const float av[4] = {a4.x, a4.y, a4.z, a4.w};
            const float wv[4] = {w4.x, w4.y, w4.z, w4.w};
            #pragma unroll
            for (int u = 0; u < 4; ++u)
                #pragma unroll
                for (int v = 0; v < 4; ++v)
                    acc[u][v] = fmaf(av[u], wv[v], acc[u][v]);
        }
        __syncthreads();
    }

    float* p = part + (size_t)blockIdx.z * TMP_ELEMS;
    #pragma unroll
    for (int u = 0; u < 4; ++u) {
        const int b = b0 + ty * 4 + u;
        *(float4*)&p[b * CT + c0 + tx * 4] =
            make_float4(acc[u][0], acc[u][1], acc[u][2], acc[u][3]);
    }
}

// ---------------- K_RED: tmp = sum_s partials; negA = -exp(A_log) -----------
// grid: 512 blocks x 256 = 131072 = 49152 + 81920
__global__ __launch_bounds__(256) void k_red(const float* __restrict__ part,
                                             const float* __restrict__ Alog,
                                             float* __restrict__ tmp,
                                             float* __restrict__ negA) {
    const int idx = blockIdx.x * 256 + threadIdx.x;
    if (idx < TMP_ELEMS) {
        float s = 0.f;
        #pragma unroll
        for (int z = 0; z < NSPLIT; ++z) s += part[(size_t)z * TMP_ELEMS + idx];
        tmp[idx] = s;
    } else {
        const int j = idx - TMP_ELEMS;
        negA[j] = -__expf(Alog[j]);
    }
}

// ---------------- K_FUSED: dt dot-product + SSM epilogue --------------------
// dt[b,d] = softplus(sum_k t[b,k]*Wdt[k,d] + bdt[d])
// y[b,d]  = sum_n (exp(negA[d,n]*dt)*h0[b,d,n] + dt*x*Bm[b,n]) * Cm[b,n] + x
// v5 = r5 structure (LDS t, 4 b/thread, no prefetch) + NONTEMPORAL h0/x/out.
// Theory: the 84 MB h0 stream was evicting the shared Wdt panel from L2, so
// each of 1280 blocks pulled its 164 KB Wdt panel from L3 (~210 MB of L3
// traffic -> L3-BW-bound at ~49 us). 'nt' on the streams keeps Wdt
// L2-resident (3.3 MB total, fits per-XCD L2); Wdt/negA/tmp stay cached.
__global__ __launch_bounds__(256) void k_fused(const float* __restrict__ x,
                                               const float* __restrict__ h0,
                                               const float* __restrict__ Wdt,
                                               const float* __restrict__ bdt,
                                               const float* __restrict__ tmp,
                                               const float* __restrict__ negA,
                                               float* __restrict__ out) {
    __shared__ float ts[4][CT];        // 4 rows of t(160)+Bm(16)+Cm(16)
    const int tid = threadIdx.x;
    const int b0 = blockIdx.x * 4;     // fast axis: shares Wdt panel
    const int d  = blockIdx.y * 256 + tid;

    // stage 4 t/BC rows (768 floats), coalesced, one barrier
    for (int p = tid; p < 4 * CT; p += 256)
        ts[p / CT][p % CT] = tmp[(size_t)b0 * CT + p];
    __syncthreads();

    // ---- dt dot-product: only Wdt touches vmem (cached); t from LDS ----
    const float* wcol = Wdt + d;
    float acc[4] = {0.f, 0.f, 0.f, 0.f};
    #pragma unroll 2
    for (int k8 = 0; k8 < RR; k8 += 8) {
        float w[8];
        #pragma unroll
        for (int j = 0; j < 8; ++j) w[j] = wcol[(size_t)(k8 + j) * DD];
        #pragma unroll
        for (int bi = 0; bi < 4; ++bi) {
            const float* tr = &ts[bi][k8];
            #pragma unroll
            for (int j = 0; j < 8; ++j)
                acc[bi] = fmaf(tr[j], w[j], acc[bi]);
        }
    }

    // negA[d, 0..15] into registers (cached: 64 blocks share this panel)
    float av[16];
    {
        const float* ap = &negA[(size_t)d * NN];
        #pragma unroll
        for (int n4 = 0; n4 < NN; n4 += 4) {
            const float4 a4 = *(const float4*)&ap[n4];
            av[n4 + 0] = a4.x; av[n4 + 1] = a4.y;
            av[n4 + 2] = a4.z; av[n4 + 3] = a4.w;
        }
    }
    const float bdv = bdt[d];

    // ---- epilogue: softplus + SSM; h0/x/out NONTEMPORAL (stream once) ----
    #pragma unroll
    for (int bi = 0; bi < 4; ++bi) {
        const float z  = acc[bi] + bdv;
        const float dt = fmaxf(z, 0.f) + log1pf(__expf(-fabsf(z)));  // softplus
        const size_t cell = (size_t)(b0 + bi) * DD + d;
        const float xe  = __builtin_nontemporal_load(&x[cell]);
        const float dtx = dt * xe;
        const float* hp = &h0[cell * NN];
        const float* bm = &ts[bi][RR];       // Bm from LDS (broadcast)
        const float* cm = &ts[bi][RR + 16];  // Cm from LDS
        float acc4[4] = {xe, 0.f, 0.f, 0.f};
        #pragma unroll
        for (int n4 = 0; n4 < NN; n4 += 4) {
            const vfloat4 h4 = __builtin_nontemporal_load((const vfloat4*)&hp[n4]);
            const float hv[4] = {h4.x, h4.y, h4.z, h4.w};
            #pragma unroll
            for (int q = 0; q < 4; ++q) {
                const int n = n4 + q;
                const float dA = __expf(av[n] * dt);
                const float h  = fmaf(dA, hv[q], dtx * bm[n]);
                acc4[q] = fmaf(h, cm[n], acc4[q]);
            }
        }
        const float yv = (acc4[0] + acc4[1]) + (acc4[2] + acc4[3]);
        __builtin_nontemporal_store(yv, &out[cell]);
    }
}

extern "C" void kernel_launch(void* const* d_in, const int* in_sizes, int n_in,
                              void* d_out, int out_size, void* d_ws, size_t ws_size,
                              hipStream_t stream) {
    const float* x    = (const float*)d_in[0];
    const float* h0   = (const float*)d_in[1];
    const float* Wxdt = (const float*)d_in[2];
    const float* Wdt  = (const float*)d_in[3];
    const float* bdt  = (const float*)d_in[4];
    const float* Wbc  = (const float*)d_in[5];
    const float* Alog = (const float*)d_in[6];
    float* out = (float*)d_out;

    // ws layout (floats): partials[32*49152] | tmp[49152] | negA[81920]
    float* part = (float*)d_ws;
    float* tmp  = part + (size_t)NSPLIT * TMP_ELEMS;
    float* negA = tmp + TMP_ELEMS;

    k1_gemm<<<dim3(3, 4, NSPLIT), 256, 0, stream>>>(x, Wxdt, Wbc, part);
    k_red<<<dim3((TMP_ELEMS + NEGA_ELEMS) / 256), 256, 0, stream>>>(part, Alog, tmp, negA);
    k_fused<<<dim3(BB / 4, DD / 256), 256, 0, stream>>>(x, h0, Wdt, bdt, tmp, negA, out);
}

// Round 9
// 175.628 us; speedup vs baseline: 1.0783x; 1.0173x over previous
//
#include <hip/hip_runtime.h>
#include <math.h>

#define BB 256
#define DD 5120
#define NN 16
#define RR 160
#define CT 192          // 160 (t) + 16 (Bm) + 16 (Cm)
#define NSPLIT 32
#define TMP_ELEMS (BB * CT)          // 49152
#define NEGA_ELEMS (DD * NN)         // 81920

// ---------------- K1: partials[s][b][c] = x[b, ks:ks+160] @ Wcat[ks:ks+160, c]
// grid: (3 c-tiles, 4 b-tiles, 32 k-splits), block 256. No atomics.
// (Exact round-1 version — part of the measured-best 175 us configs.)
__global__ __launch_bounds__(256) void k1_gemm(const float* __restrict__ x,
                                               const float* __restrict__ Wxdt,
                                               const float* __restrict__ Wbc,
                                               float* __restrict__ part) {
    __shared__ float xs[32][68];   // [k][b] transposed (68: b128-aligned rows)
    __shared__ float ws[32][64];   // [k][c]
    const int tid = threadIdx.x;
    const int tx = tid & 15, ty = tid >> 4;
    const int c0 = blockIdx.x * 64;
    const int b0 = blockIdx.y * 64;
    const int k0 = blockIdx.z * 160;
    float acc[4][4] = {};

    for (int kc = 0; kc < 160; kc += 32) {
        // stage x tile transposed into LDS
        {
            const int i  = tid >> 3;          // 0..31
            const int j4 = (tid & 7) * 4;     // 0..28
            #pragma unroll
            for (int rep = 0; rep < 2; ++rep) {
                const int row = i + rep * 32;
                const float4 v = *(const float4*)&x[(size_t)(b0 + row) * DD + k0 + kc + j4];
                xs[j4 + 0][row] = v.x;
                xs[j4 + 1][row] = v.y;
                xs[j4 + 2][row] = v.z;
                xs[j4 + 3][row] = v.w;
            }
        }
        // stage W tile (float4 along c; both sources are %4 aligned)
        {
            const int c4 = (tid & 15) * 4;
            const int r0 = tid >> 4;          // 0..15
            #pragma unroll
            for (int rep = 0; rep < 2; ++rep) {
                const int r  = r0 + rep * 16;
                const int kg = k0 + kc + r;
                const int cg = c0 + c4;
                float4 v;
                if (cg < RR) v = *(const float4*)&Wxdt[(size_t)kg * RR + cg];
                else         v = *(const float4*)&Wbc[(size_t)kg * 32 + (cg - RR)];
                *(float4*)&ws[r][c4] = v;
            }
        }
        __syncthreads();
        #pragma unroll
        for (int k = 0; k < 32; ++k) {
            const float4 a4 = *(const float4*)&xs[k][ty * 4];
            const float4 w4 = *(const float4*)&ws[k][tx * 4];
            const float av[4] = {a4.x, a4.y, a4.z, a4.w};
            const float wv[4] = {w4.x, w4.y, w4.z, w4.w};
            #pragma unroll
            for (int u = 0; u < 4; ++u)
                #pragma unroll
                for (int v = 0; v < 4; ++v)
                    acc[u][v] = fmaf(av[u], wv[v], acc[u][v]);
        }
        __syncthreads();
    }

    float* p = part + (size_t)blockIdx.z * TMP_ELEMS;
    #pragma unroll
    for (int u = 0; u < 4; ++u) {
        const int b = b0 + ty * 4 + u;
        *(float4*)&p[b * CT + c0 + tx * 4] =
            make_float4(acc[u][0], acc[u][1], acc[u][2], acc[u][3]);
    }
}

// ---------------- K_RED: tmp = sum_s partials; negA = -exp(A_log) -----------
// grid: 512 blocks x 256 = 131072 = 49152 + 81920
__global__ __launch_bounds__(256) void k_red(const float* __restrict__ part,
                                             const float* __restrict__ Alog,
                                             float* __restrict__ tmp,
                                             float* __restrict__ negA) {
    const int idx = blockIdx.x * 256 + threadIdx.x;
    if (idx < TMP_ELEMS) {
        float s = 0.f;
        #pragma unroll
        for (int z = 0; z < NSPLIT; ++z) s += part[(size_t)z * TMP_ELEMS + idx];
        tmp[idx] = s;
    } else {
        const int j = idx - TMP_ELEMS;
        negA[j] = -__expf(Alog[j]);
    }
}

// ---------------- K_FUSED: dt dot-product + SSM epilogue --------------------
// dt[b,d] = softplus(sum_k t[b,k]*Wdt[k,d] + bdt[d])
// y[b,d]  = sum_n (exp(negA[d,n]*dt)*h0[b,d,n] + dt*x*Bm[b,n]) * Cm[b,n] + x
// v6 = r5 structure with ALL ts/bm/cm LDS reads vectorized to float4.
// Theory: every prior variant paid ~45 us in the LDS pipe on scalar
// ds_read_b32 broadcasts (960/wave x 5.8 cy x 20 waves/CU). ds_read_b128
// (12 cy for 4 values) cuts the dt-loop LDS-pipe time ~2.7x, dropping
// k_fused toward its ~15 us h0-stream floor.
__global__ __launch_bounds__(256) void k_fused(const float* __restrict__ x,
                                               const float* __restrict__ h0,
                                               const float* __restrict__ Wdt,
                                               const float* __restrict__ bdt,
                                               const float* __restrict__ tmp,
                                               const float* __restrict__ negA,
                                               float* __restrict__ out) {
    __shared__ float ts[4][CT];        // 4 rows of t(160)+Bm(16)+Cm(16); rows 768B (16B-aligned)
    const int tid = threadIdx.x;
    const int b0 = blockIdx.x * 4;     // fast axis: shares Wdt panel
    const int d  = blockIdx.y * 256 + tid;

    // stage 4 t/BC rows (768 floats), coalesced, one barrier
    for (int p = tid; p < 4 * CT; p += 256)
        ts[p / CT][p % CT] = tmp[(size_t)b0 * CT + p];
    __syncthreads();

    // ---- dt dot-product: Wdt via coalesced vmem; t via ds_read_b128 ----
    const float* wcol = Wdt + d;
    float acc[4] = {0.f, 0.f, 0.f, 0.f};
    #pragma unroll 2
    for (int k8 = 0; k8 < RR; k8 += 8) {
        float w[8];
        #pragma unroll
        for (int j = 0; j < 8; ++j) w[j] = wcol[(size_t)(k8 + j) * DD];
        #pragma unroll
        for (int bi = 0; bi < 4; ++bi) {
            const float4 ta = *(const float4*)&ts[bi][k8];      // ds_read_b128 broadcast
            const float4 tb = *(const float4*)&ts[bi][k8 + 4];  // ds_read_b128 broadcast
            acc[bi] = fmaf(ta.x, w[0], acc[bi]);
            acc[bi] = fmaf(ta.y, w[1], acc[bi]);
            acc[bi] = fmaf(ta.z, w[2], acc[bi]);
            acc[bi] = fmaf(ta.w, w[3], acc[bi]);
            acc[bi] = fmaf(tb.x, w[4], acc[bi]);
            acc[bi] = fmaf(tb.y, w[5], acc[bi]);
            acc[bi] = fmaf(tb.z, w[6], acc[bi]);
            acc[bi] = fmaf(tb.w, w[7], acc[bi]);
        }
    }

    // negA[d, 0..15] into registers (reused across the 4 b's)
    float av[16];
    {
        const float* ap = &negA[(size_t)d * NN];
        #pragma unroll
        for (int n4 = 0; n4 < NN; n4 += 4) {
            const float4 a4 = *(const float4*)&ap[n4];
            av[n4 + 0] = a4.x; av[n4 + 1] = a4.y;
            av[n4 + 2] = a4.z; av[n4 + 3] = a4.w;
        }
    }
    const float bdv = bdt[d];

    // ---- epilogue: softplus + SSM; Bm/Cm via ds_read_b128 ----
    #pragma unroll
    for (int bi = 0; bi < 4; ++bi) {
        const float z  = acc[bi] + bdv;
        const float dt = fmaxf(z, 0.f) + log1pf(__expf(-fabsf(z)));  // softplus
        const size_t cell = (size_t)(b0 + bi) * DD + d;
        const float xe  = x[cell];
        const float dtx = dt * xe;
        const float* hp = &h0[cell * NN];
        float bm[16], cm[16];
        #pragma unroll
        for (int n4 = 0; n4 < NN; n4 += 4) {
            const float4 bv4 = *(const float4*)&ts[bi][RR + n4];       // b128
            const float4 cv4 = *(const float4*)&ts[bi][RR + 16 + n4];  // b128
            bm[n4 + 0] = bv4.x; bm[n4 + 1] = bv4.y; bm[n4 + 2] = bv4.z; bm[n4 + 3] = bv4.w;
            cm[n4 + 0] = cv4.x; cm[n4 + 1] = cv4.y; cm[n4 + 2] = cv4.z; cm[n4 + 3] = cv4.w;
        }
        float acc4[4] = {xe, 0.f, 0.f, 0.f};
        #pragma unroll
        for (int n4 = 0; n4 < NN; n4 += 4) {
            const float4 h4 = *(const float4*)&hp[n4];
            const float hv[4] = {h4.x, h4.y, h4.z, h4.w};
            #pragma unroll
            for (int q = 0; q < 4; ++q) {
                const int n = n4 + q;
                const float dA = __expf(av[n] * dt);
                const float h  = fmaf(dA, hv[q], dtx * bm[n]);
                acc4[q] = fmaf(h, cm[n], acc4[q]);
            }
        }
        out[cell] = (acc4[0] + acc4[1]) + (acc4[2] + acc4[3]);
    }
}

extern "C" void kernel_launch(void* const* d_in, const int* in_sizes, int n_in,
                              void* d_out, int out_size, void* d_ws, size_t ws_size,
                              hipStream_t stream) {
    const float* x    = (const float*)d_in[0];
    const float* h0   = (const float*)d_in[1];
    const float* Wxdt = (const float*)d_in[2];
    const float* Wdt  = (const float*)d_in[3];
    const float* bdt  = (const float*)d_in[4];
    const float* Wbc  = (const float*)d_in[5];
    const float* Alog = (const float*)d_in[6];
    float* out = (float*)d_out;

    // ws layout (floats): partials[32*49152] | tmp[49152] | negA[81920]
    float* part = (float*)d_ws;
    float* tmp  = part + (size_t)NSPLIT * TMP_ELEMS;
    float* negA = tmp + TMP_ELEMS;

    k1_gemm<<<dim3(3, 4, NSPLIT), 256, 0, stream>>>(x, Wxdt, Wbc, part);
    k_red<<<dim3((TMP_ELEMS + NEGA_ELEMS) / 256), 256, 0, stream>>>(part, Alog, tmp, negA);
    k_fused<<<dim3(BB / 4, DD / 256), 256, 0, stream>>>(x, h0, Wdt, bdt, tmp, negA, out);
}

// Round 10
// 173.410 us; speedup vs baseline: 1.0921x; 1.0128x over previous
//
#include <hip/hip_runtime.h>
#include <math.h>

#define BB 256
#define DD 5120
#define NN 16
#define RR 160
#define CT 192          // 160 (t) + 16 (Bm) + 16 (Cm)
#define NSPLIT 40
#define K1_KRANGE 128   // 40 * 128 = 5120
#define TMP_ELEMS (BB * CT)          // 49152
#define NEGA_ELEMS (DD * NN)         // 81920

// ---------------- K1: partials[s][b][c] = x[b, ks:ks+128] @ Wcat[ks:ks+128, c]
// Round-1 tile/micro structure, KRANGE 160->128: 4 kc-phases per block,
// grid (3 c, 4 b, 40 ksplits) = 480 blocks (+25% CU coverage).
__global__ __launch_bounds__(256) void k1_gemm(const float* __restrict__ x,
                                               const float* __restrict__ Wxdt,
                                               const float* __restrict__ Wbc,
                                               float* __restrict__ part) {
    __shared__ float xs[32][68];   // [k][b] transposed (68: b128-aligned rows)
    __shared__ float ws[32][64];   // [k][c]
    const int tid = threadIdx.x;
    const int tx = tid & 15, ty = tid >> 4;
    const int c0 = blockIdx.x * 64;
    const int b0 = blockIdx.y * 64;
    const int k0 = blockIdx.z * K1_KRANGE;
    float acc[4][4] = {};

    for (int kc = 0; kc < K1_KRANGE; kc += 32) {
        // stage x tile transposed into LDS
        {
            const int i  = tid >> 3;          // 0..31
            const int j4 = (tid & 7) * 4;     // 0..28
            #pragma unroll
            for (int rep = 0; rep < 2; ++rep) {
                const int row = i + rep * 32;
                const float4 v = *(const float4*)&x[(size_t)(b0 + row) * DD + k0 + kc + j4];
                xs[j4 + 0][row] = v.x;
                xs[j4 + 1][row] = v.y;
                xs[j4 + 2][row] = v.z;
                xs[j4 + 3][row] = v.w;
            }
        }
        // stage W tile (float4 along c; both sources are %4 aligned)
        {
            const int c4 = (tid & 15) * 4;
            const int r0 = tid >> 4;          // 0..15
            #pragma unroll
            for (int rep = 0; rep < 2; ++rep) {
                const int r  = r0 + rep * 16;
                const int kg = k0 + kc + r;
                const int cg = c0 + c4;
                float4 v;
                if (cg < RR) v = *(const float4*)&Wxdt[(size_t)kg * RR + cg];
                else         v = *(const float4*)&Wbc[(size_t)kg * 32 + (cg - RR)];
                *(float4*)&ws[r][c4] = v;
            }
        }
        __syncthreads();
        #pragma unroll
        for (int k = 0; k < 32; ++k) {
            const float4 a4 = *(const float4*)&xs[k][ty * 4];
            const float4 w4 = *(const float4*)&ws[k][tx * 4];
            const float av[4] = {a4.x, a4.y, a4.z, a4.w};
            const float wv[4] = {w4.x, w4.y, w4.z, w4.w};
            #pragma unroll
            for (int u = 0; u < 4; ++u)
                #pragma unroll
                for (int v = 0; v < 4; ++v)
                    acc[u][v] = fmaf(av[u], wv[v], acc[u][v]);
        }
        __syncthreads();
    }

    float* p = part + (size_t)blockIdx.z * TMP_ELEMS;
    #pragma unroll
    for (int u = 0; u < 4; ++u) {
        const int b = b0 + ty * 4 + u;
        *(float4*)&p[b * CT + c0 + tx * 4] =
            make_float4(acc[u][0], acc[u][1], acc[u][2], acc[u][3]);
    }
}

// ---------------- K_RED: tmp = sum_s partials; negA = -exp(A_log) -----------
// grid: 512 blocks x 256 = 131072 = 49152 + 81920
__global__ __launch_bounds__(256) void k_red(const float* __restrict__ part,
                                             const float* __restrict__ Alog,
                                             float* __restrict__ tmp,
                                             float* __restrict__ negA) {
    const int idx = blockIdx.x * 256 + threadIdx.x;
    if (idx < TMP_ELEMS) {
        float s = 0.f;
        #pragma unroll
        for (int z = 0; z < NSPLIT; ++z) s += part[(size_t)z * TMP_ELEMS + idx];
        tmp[idx] = s;
    } else {
        const int j = idx - TMP_ELEMS;
        negA[j] = -__expf(Alog[j]);
    }
}

// ---------------- K_FUSED: dt dot-product + SSM epilogue --------------------
// dt[b,d] = softplus(sum_k t[b,k]*Wdt[k,d] + bdt[d])
// y[b,d]  = sum_n (exp(negA[d,n]*dt)*h0[b,d,n] + dt*x*Bm[b,n]) * Cm[b,n] + x
// v7 = r9 structure with 8 b PER THREAD (640 blocks): halves the redundant
// Wdt panel traffic (210 -> 105 MB), the one axis with a measured slope
// (r3->r6: doubling panel traffic cost +10 us => ~21 TB/s marginal BW).
// Also doubles FMA per load batch inside the dt loop (better in-loop cover).
__global__ __launch_bounds__(256) void k_fused(const float* __restrict__ x,
                                               const float* __restrict__ h0,
                                               const float* __restrict__ Wdt,
                                               const float* __restrict__ bdt,
                                               const float* __restrict__ tmp,
                                               const float* __restrict__ negA,
                                               float* __restrict__ out) {
    __shared__ float ts[8][CT];        // 8 rows of t(160)+Bm(16)+Cm(16); rows 768B
    const int tid = threadIdx.x;
    const int b0 = blockIdx.x * 8;     // fast axis: shares Wdt panel
    const int d  = blockIdx.y * 256 + tid;

    // stage 8 t/BC rows (1536 floats), coalesced, one barrier
    for (int p = tid; p < 8 * CT; p += 256)
        ts[p / CT][p % CT] = tmp[(size_t)b0 * CT + p];
    __syncthreads();

    // ---- dt dot-product: Wdt via coalesced vmem; t via ds_read_b128 ----
    const float* wcol = Wdt + d;
    float acc[8] = {};
    for (int k8 = 0; k8 < RR; k8 += 8) {
        float w[8];
        #pragma unroll
        for (int j = 0; j < 8; ++j) w[j] = wcol[(size_t)(k8 + j) * DD];
        #pragma unroll
        for (int bi = 0; bi < 8; ++bi) {
            const float4 ta = *(const float4*)&ts[bi][k8];      // ds_read_b128 broadcast
            const float4 tb = *(const float4*)&ts[bi][k8 + 4];  // ds_read_b128 broadcast
            acc[bi] = fmaf(ta.x, w[0], acc[bi]);
            acc[bi] = fmaf(ta.y, w[1], acc[bi]);
            acc[bi] = fmaf(ta.z, w[2], acc[bi]);
            acc[bi] = fmaf(ta.w, w[3], acc[bi]);
            acc[bi] = fmaf(tb.x, w[4], acc[bi]);
            acc[bi] = fmaf(tb.y, w[5], acc[bi]);
            acc[bi] = fmaf(tb.z, w[6], acc[bi]);
            acc[bi] = fmaf(tb.w, w[7], acc[bi]);
        }
    }

    // negA[d, 0..15] into registers (reused across the 8 b's)
    float av[16];
    {
        const float* ap = &negA[(size_t)d * NN];
        #pragma unroll
        for (int n4 = 0; n4 < NN; n4 += 4) {
            const float4 a4 = *(const float4*)&ap[n4];
            av[n4 + 0] = a4.x; av[n4 + 1] = a4.y;
            av[n4 + 2] = a4.z; av[n4 + 3] = a4.w;
        }
    }
    const float bdv = bdt[d];

    // ---- epilogue: softplus + SSM; Bm/Cm via ds_read_b128 ----
    #pragma unroll
    for (int bi = 0; bi < 8; ++bi) {
        const float z  = acc[bi] + bdv;
        const float dt = fmaxf(z, 0.f) + log1pf(__expf(-fabsf(z)));  // softplus
        const size_t cell = (size_t)(b0 + bi) * DD + d;
        const float xe  = x[cell];
        const float dtx = dt * xe;
        const float* hp = &h0[cell * NN];
        float bm[16], cm[16];
        #pragma unroll
        for (int n4 = 0; n4 < NN; n4 += 4) {
            const float4 bv4 = *(const float4*)&ts[bi][RR + n4];       // b128
            const float4 cv4 = *(const float4*)&ts[bi][RR + 16 + n4];  // b128
            bm[n4 + 0] = bv4.x; bm[n4 + 1] = bv4.y; bm[n4 + 2] = bv4.z; bm[n4 + 3] = bv4.w;
            cm[n4 + 0] = cv4.x; cm[n4 + 1] = cv4.y; cm[n4 + 2] = cv4.z; cm[n4 + 3] = cv4.w;
        }
        float acc4[4] = {xe, 0.f, 0.f, 0.f};
        #pragma unroll
        for (int n4 = 0; n4 < NN; n4 += 4) {
            const float4 h4 = *(const float4*)&hp[n4];
            const float hv[4] = {h4.x, h4.y, h4.z, h4.w};
            #pragma unroll
            for (int q = 0; q < 4; ++q) {
                const int n = n4 + q;
                const float dA = __expf(av[n] * dt);
                const float h  = fmaf(dA, hv[q], dtx * bm[n]);
                acc4[q] = fmaf(h, cm[n], acc4[q]);
            }
        }
        out[cell] = (acc4[0] + acc4[1]) + (acc4[2] + acc4[3]);
    }
}

extern "C" void kernel_launch(void* const* d_in, const int* in_sizes, int n_in,
                              void* d_out, int out_size, void* d_ws, size_t ws_size,
                              hipStream_t stream) {
    const float* x    = (const float*)d_in[0];
    const float* h0   = (const float*)d_in[1];
    const float* Wxdt = (const float*)d_in[2];
    const float* Wdt  = (const float*)d_in[3];
    const float* bdt  = (const float*)d_in[4];
    const float* Wbc  = (const float*)d_in[5];
    const float* Alog = (const float*)d_in[6];
    float* out = (float*)d_out;

    // ws layout (floats): partials[40*49152] (7.9 MB) | tmp[49152] | negA[81920]
    float* part = (float*)d_ws;
    float* tmp  = part + (size_t)NSPLIT * TMP_ELEMS;
    float* negA = tmp + TMP_ELEMS;

    k1_gemm<<<dim3(3, 4, NSPLIT), 256, 0, stream>>>(x, Wxdt, Wbc, part);
    k_red<<<dim3((TMP_ELEMS + NEGA_ELEMS) / 256), 256, 0, stream>>>(part, Alog, tmp, negA);
    k_fused<<<dim3(BB / 8, DD / 256), 256, 0, stream>>>(x, h0, Wdt, bdt, tmp, negA, out);
}